// Round 10
// baseline (217.553 us; speedup 1.0000x reference)
//
#include <hip/hip_runtime.h>

// Problem: B=4, S=2048, D_IN=1024, D_OUT=1024, H=16, DH=64
#define NB 4
#define NS 2048
#define NH 16
#define NDH 64

typedef short bf16x8 __attribute__((ext_vector_type(8)));
typedef short bf16x4 __attribute__((ext_vector_type(4)));
typedef float f32x4 __attribute__((ext_vector_type(4)));
typedef unsigned short u16;
typedef unsigned int u32;

static __device__ __forceinline__ u16 f2bf(float f) {
  unsigned u = __float_as_uint(f);
  u += 0x7fffu + ((u >> 16) & 1u);  // round-to-nearest-even
  return (u16)(u >> 16);
}

#define GLDS(gp, lp) __builtin_amdgcn_global_load_lds( \
    (const __attribute__((address_space(1))) void*)(gp), \
    (__attribute__((address_space(3))) void*)(lp), 16, 0, 0)

// ---------------- fp32 -> bf16 elementwise convert ----------------
__global__ void cvt_k(const float* __restrict__ in, u16* __restrict__ out, int n) {
  int i = (blockIdx.x * 256 + threadIdx.x) * 8;
  if (i >= n) return;
  float4 a = *(const float4*)&in[i];
  float4 b = *(const float4*)&in[i + 4];
  bf16x8 u;
  u[0] = (short)f2bf(a.x); u[1] = (short)f2bf(a.y);
  u[2] = (short)f2bf(a.z); u[3] = (short)f2bf(a.w);
  u[4] = (short)f2bf(b.x); u[5] = (short)f2bf(b.y);
  u[6] = (short)f2bf(b.z); u[7] = (short)f2bf(b.w);
  *(bf16x8*)&out[i] = u;
}

// ---------------- fp32 [R][C] -> bf16 [C][R] transpose-convert ----------------
__global__ void trcvt_k(const float* __restrict__ in, u16* __restrict__ out, int R, int C) {
  __shared__ float t[32][33];
  int c0 = blockIdx.x * 32, r0 = blockIdx.y * 32;
  int tx = threadIdx.x & 7, ty = threadIdx.x >> 3;
  float4 v = *(const float4*)&in[(size_t)(r0 + ty) * C + c0 + tx * 4];
  t[ty][tx * 4 + 0] = v.x; t[ty][tx * 4 + 1] = v.y;
  t[ty][tx * 4 + 2] = v.z; t[ty][tx * 4 + 3] = v.w;
  __syncthreads();
  ushort4 o;
  o.x = f2bf(t[tx * 4 + 0][ty]); o.y = f2bf(t[tx * 4 + 1][ty]);
  o.z = f2bf(t[tx * 4 + 2][ty]); o.w = f2bf(t[tx * 4 + 3][ty]);
  *(ushort4*)&out[(size_t)(c0 + ty) * R + r0 + tx * 4] = o;
}

// ---------------- bf16 GEMM, 256x128 tile, BK=32, 8 waves, dbuf prefetch ----------------
// A [M][K] row-major, Bt [N][K] row-major. Wave-grid 4(M)x2(N); wave-tile 64x64.
// Double-buffered LDS (48KB, 3 blocks/CU); STAGE(kt+1) issued before compute(kt),
// single barrier per K-step (attn-R9 structure).
// MODE 0: scatter into Q (pre-scaled by 0.125*log2e) [bh][s][dh], K [bh][s][dh],
//         VT [bh][dh][s].
// MODE 1: fp32 out [M][N] with bias added.
template<int MODE>
__global__ __launch_bounds__(512)
void gemm_k(const u16* __restrict__ A, const u16* __restrict__ Bt,
            int M, int N, int K,
            u16* __restrict__ Qo, u16* __restrict__ Ko, u16* __restrict__ VTo,
            float* __restrict__ Co, const float* __restrict__ bias) {
  __shared__ __align__(16) u16 As[2][256 * 32];
  __shared__ __align__(16) u16 Bs[2][128 * 32];
  const int tid = threadIdx.x;
  const int w = tid >> 6, l = tid & 63;
  const int lr = l & 15, lg = l >> 4;
  const int wr = w >> 1, wc = w & 1;       // 4 M-waves x 2 N-waves
  const int m0 = blockIdx.y * 256, n0 = blockIdx.x * 128;

  f32x4 acc[4][4] = {};

  // staging maps (lane-linear dest; see GLDS wave-uniform-base rule)
  const int arow0 = tid >> 2;              // A round 0: rows 0..127
  const int arow1 = 128 + (tid >> 2);      // A round 1: rows 128..255
  const int brow  = tid >> 2;              // B: rows 0..127
  const int scol  = (tid & 3) * 8;         // elems 0,8,16,24
  const int abase0 = (w * 64) * 16;        // byte base, round 0
  const int abase1 = (512 + w * 64) * 16;  // byte base, round 1
  const int bbase  = (w * 64) * 16;

#define STAGE(kt, buf) do {                                              \
    const int k0_ = (kt) * 32;                                           \
    GLDS(A  + (size_t)(m0 + arow0) * K + k0_ + scol, (char*)As[buf] + abase0); \
    GLDS(A  + (size_t)(m0 + arow1) * K + k0_ + scol, (char*)As[buf] + abase1); \
    GLDS(Bt + (size_t)(n0 + brow ) * K + k0_ + scol, (char*)Bs[buf] + bbase);  \
  } while (0)

  const int nk = K >> 5;
  STAGE(0, 0);
  __syncthreads();   // drains vmcnt(0): tile 0 staged

  for (int kt = 0; kt < nk; ++kt) {
    const int cur = kt & 1;
    if (kt + 1 < nk) STAGE(kt + 1, cur ^ 1);   // prefetch; lands under compute

    bf16x8 af[4];
#pragma unroll
    for (int mi = 0; mi < 4; ++mi)
      af[mi] = *(const bf16x8*)&As[cur][(wr * 64 + mi * 16 + lr) * 32 + lg * 8];
#pragma unroll
    for (int ni = 0; ni < 4; ++ni) {
      bf16x8 bfr = *(const bf16x8*)&Bs[cur][(wc * 64 + ni * 16 + lr) * 32 + lg * 8];
#pragma unroll
      for (int mi = 0; mi < 4; ++mi)
        acc[mi][ni] = __builtin_amdgcn_mfma_f32_16x16x32_bf16(af[mi], bfr, acc[mi][ni], 0, 0, 0);
    }

    __syncthreads();   // drains prefetch + protects buffer reuse
  }

#pragma unroll
  for (int mi = 0; mi < 4; ++mi) {
#pragma unroll
    for (int ni = 0; ni < 4; ++ni) {
#pragma unroll
      for (int r = 0; r < 4; ++r) {
        int gm = m0 + wr * 64 + mi * 16 + lg * 4 + r;
        int gn = n0 + wc * 64 + ni * 16 + lr;
        float v = acc[mi][ni][r];
        if (MODE == 0) {
          int which = gn >> 10, hd = gn & 1023;
          int b = gm >> 11, s = gm & 2047;
          int bh = b * NH + (hd >> 6), dh = hd & 63;
          if (which == 0)      Qo[((size_t)bh * NS + s) * NDH + dh] = f2bf(v * 0.1803368801111204f);
          else if (which == 1) Ko[((size_t)bh * NS + s) * NDH + dh] = f2bf(v);
          else                 VTo[((size_t)bh * NDH + dh) * NS + s] = f2bf(v);
        } else {
          Co[(size_t)gm * N + gn] = v + bias[gn];
        }
      }
    }
  }
#undef STAGE
}

// ---------------- causal flash attention, swapped-QK^T, in-register P ----------------
// Q (pre-scaled),K: [bh][S][DH] bf16; VT: [bh][DH][S] bf16. CTX: [B][S][H*DH] bf16.
// 8 WAVES (512 threads), wave w owns 16 q rows: qt*128 + w*16 + (0..15).
// TRIANGLE-PAIRED: block (bh, pr) runs q-tile `pr` then `15-pr` -> 36 K-tiles each.
// Grid (64,8): same-head blocks share an XCD L2. 2 blocks/CU = 16 waves/CU.
// KVBLK=64, double-buffered LDS (32KB); no online max (scores O(+-10) in log2
// domain); row-sum linear -> one cross-lane reduce per pass.
__global__ __launch_bounds__(512)
void attn_k(const u16* __restrict__ Q, const u16* __restrict__ Kg,
            const u16* __restrict__ VTg, u16* __restrict__ CTX) {
  const int bh = blockIdx.x;        // 0..63 (same-bh blocks -> same XCD)
  const int pr = blockIdx.y;        // 0..7
  const int tid = threadIdx.x, w = tid >> 6, l = tid & 63;
  const int lr = l & 15, lg = l >> 4;
  const u16* Qh  = Q   + (size_t)bh * NS * NDH;
  const u16* Kh  = Kg  + (size_t)bh * NS * NDH;
  const u16* Vth = VTg + (size_t)bh * NDH * NS;

  __shared__ __align__(16) u16 Ks[2][64 * 64];  // [key][dh], XOR-swizzled content
  __shared__ __align__(16) u16 Vs[2][64 * 64];  // [dh][key], XOR-swizzled content

  // staging: 512 threads x 16B x (K,V) = full 8KB K-tile + 8KB V-tile in one round.
  // LDS dest lane-linear (GLDS); source pre-applies the inverse swizzle (rule #21).
  const int srow_ = tid >> 3;              // 0..63
  const int colb  = (tid & 7) * 16;        // byte col within 128B row
  const int scolb = colb ^ ((srow_ & 7) << 4);
  const int kSrcOff = srow_ * NDH + (scolb >> 1);  // elems into K tile (stride 64)
  const int vSrcOff = srow_ * NS + (scolb >> 1);   // elems into VT (stride 2048)
  const int ldsOff  = w * 1024;            // wave-uniform byte base (64 lanes x 16B)

#define STAGE(t, buf) do {                                          \
    GLDS(Kh  + (size_t)(t) * 64 * NDH + kSrcOff, (char*)Ks[buf] + ldsOff); \
    GLDS(Vth + (size_t)(t) * 64       + vSrcOff, (char*)Vs[buf] + ldsOff); \
  } while (0)

  const int swz = (lr & 7) << 4;
  const int b = bh >> 4, h = bh & 15;

  for (int pass = 0; pass < 2; ++pass) {
    const int qt = pass == 0 ? pr : 15 - pr;

    // Q fragments (B operand): col = q = lr, k(dh) = kk*32 + lg*8 + j
    const int qrow = qt * 128 + w * 16 + lr;
    bf16x8 qf[2];
    qf[0] = *(const bf16x8*)&Qh[(size_t)qrow * NDH + 0 * 32 + lg * 8];
    qf[1] = *(const bf16x8*)&Qh[(size_t)qrow * NDH + 1 * 32 + lg * 8];

    f32x4 o[4] = {};
    float lrun = 0.f;                 // per-lane PARTIAL row-sum
    const int qmin = qt * 128 + w * 16;   // wave's lowest q row

    __syncthreads();   // all waves done reading previous pass's LDS
    STAGE(0, 0);
    __syncthreads();   // drains vmcnt(0): tile 0 staged

    const int NT = 2 * qt + 2;
    for (int kt = 0; kt < NT; ++kt) {
      const int cur = kt & 1;
      if (kt + 1 < NT) STAGE(kt + 1, cur ^ 1);   // prefetch; lands under compute

      // ---- S^T = K Q^T : sc[kg][r] = S_log2[key=kt*64+kg*16+lg*4+r][q=lr] ----
      f32x4 sc[4] = {};
#pragma unroll
      for (int kk = 0; kk < 2; ++kk) {
#pragma unroll
        for (int kg = 0; kg < 4; ++kg) {
          bf16x8 kf = *(const bf16x8*)((const char*)Ks[cur] +
                       ((kg * 16 + lr) * 128 + ((kk * 64 + lg * 16) ^ swz)));
          sc[kg] = __builtin_amdgcn_mfma_f32_16x16x32_bf16(kf, qf[kk], sc[kg], 0, 0, 0);
        }
      }

      // ---- P = exp2(S) directly; accumulate partial sum (in-place into sc) ----
      float sum = 0.f;
      if (kt * 64 + 63 > qmin) {   // tile may need causal masking (wave-uniform)
#pragma unroll
        for (int kg = 0; kg < 4; ++kg)
#pragma unroll
          for (int r = 0; r < 4; ++r) {
            int kglob = kt * 64 + kg * 16 + lg * 4 + r;
            float e = (kglob > qrow) ? 0.f : exp2f(sc[kg][r]);
            sc[kg][r] = e; sum += e;
          }
      } else {
#pragma unroll
        for (int kg = 0; kg < 4; ++kg)
#pragma unroll
          for (int r = 0; r < 4; ++r) {
            float e = exp2f(sc[kg][r]);
            sc[kg][r] = e; sum += e;
          }
      }
      lrun += sum;

      // ---- PV: A = P (packed via v_cvt_pk_bf16_f32), B = V from Vs;
      //      shared k-map: key = half*32 + (j>>2)*16 + lg*4 + (j&3) ----
#pragma unroll
      for (int half = 0; half < 2; ++half) {
        union { u32 wd[4]; bf16x8 v; } pk;
#pragma unroll
        for (int w2 = 0; w2 < 4; ++w2) {
          float lo = sc[half * 2 + (w2 >> 1)][2 * (w2 & 1)];
          float hi = sc[half * 2 + (w2 >> 1)][2 * (w2 & 1) + 1];
          asm("v_cvt_pk_bf16_f32 %0, %1, %2" : "=v"(pk.wd[w2]) : "v"(lo), "v"(hi));
        }
        bf16x8 pf = pk.v;
#pragma unroll
        for (int dhg = 0; dhg < 4; ++dhg) {
          const char* vrow = (const char*)Vs[cur] + (dhg * 16 + lr) * 128;
          bf16x4 va = *(const bf16x4*)(vrow + ((half * 64 + lg * 8) ^ swz));
          bf16x4 vb = *(const bf16x4*)(vrow + ((half * 64 + 32 + lg * 8) ^ swz));
          bf16x8 vf = __builtin_shufflevector(va, vb, 0, 1, 2, 3, 4, 5, 6, 7);
          o[dhg] = __builtin_amdgcn_mfma_f32_16x16x32_bf16(pf, vf, o[dhg], 0, 0, 0);
        }
      }

      __syncthreads();   // drains prefetch + protects buffer reuse
    }

    // ---- single deferred cross-lane reduce of the row-sum, write CTX ----
    lrun += __shfl_xor(lrun, 16);
    lrun += __shfl_xor(lrun, 32);
    float linv = 1.0f / lrun;
#pragma unroll
    for (int r = 0; r < 4; ++r) {
      float lq = __shfl(linv, (l & 48) | (lg * 4 + r));
      int srow = qt * 128 + w * 16 + lg * 4 + r;
      size_t base = ((size_t)(b * NS + srow)) * (NH * NDH) + h * NDH;
#pragma unroll
      for (int dhg = 0; dhg < 4; ++dhg)
        CTX[base + dhg * 16 + lr] = f2bf(o[dhg][r] * lq);
    }
  }
#undef STAGE
}

// ---------------- launch ----------------
extern "C" void kernel_launch(void* const* d_in, const int* in_sizes, int n_in,
                              void* d_out, int out_size, void* d_ws, size_t ws_size,
                              hipStream_t stream) {
  const float* payload = (const float*)d_in[0];
  const float* w_qkv   = (const float*)d_in[1];
  const float* w_out   = (const float*)d_in[2];
  const float* b_out   = (const float*)d_in[3];
  float* out = (float*)d_out;

  char* ws = (char*)d_ws;
  size_t o0 = 0;
  u16* Xb    = (u16*)(ws + o0); o0 += (size_t)8192 * 1024 * 2;
  u16* Wqkvt = (u16*)(ws + o0); o0 += (size_t)3072 * 1024 * 2;
  u16* Woutt = (u16*)(ws + o0); o0 += (size_t)1024 * 1024 * 2;
  u16* Qb    = (u16*)(ws + o0); o0 += (size_t)64 * 2048 * 64 * 2;
  u16* Kb    = (u16*)(ws + o0); o0 += (size_t)64 * 2048 * 64 * 2;
  u16* VTb   = (u16*)(ws + o0); o0 += (size_t)64 * 64 * 2048 * 2;  // [bh][dh][s]
  u16* CTX   = Xb;  // alias: GEMM0 finishes reading Xb before attn writes CTX

  cvt_k<<<dim3(4096), dim3(256), 0, stream>>>(payload, Xb, 8192 * 1024);
  trcvt_k<<<dim3(96, 32), dim3(256), 0, stream>>>(w_qkv, Wqkvt, 1024, 3072);
  trcvt_k<<<dim3(32, 32), dim3(256), 0, stream>>>(w_out, Woutt, 1024, 1024);
  gemm_k<0><<<dim3(24, 32), dim3(512), 0, stream>>>(Xb, Wqkvt, 8192, 3072, 1024,
                                                    Qb, Kb, VTb, nullptr, nullptr);
  attn_k<<<dim3(64, 8), dim3(512), 0, stream>>>(Qb, Kb, VTb, CTX);
  gemm_k<1><<<dim3(8, 32), dim3(512), 0, stream>>>(CTX, Woutt, 8192, 1024, 1024,
                                                   nullptr, nullptr, nullptr, out, b_out);
}

// Round 11
// 198.475 us; speedup vs baseline: 1.0961x; 1.0961x over previous
//
#include <hip/hip_runtime.h>

// Problem: B=4, S=2048, D_IN=1024, D_OUT=1024, H=16, DH=64
#define NB 4
#define NS 2048
#define NH 16
#define NDH 64

typedef short bf16x8 __attribute__((ext_vector_type(8)));
typedef short bf16x4 __attribute__((ext_vector_type(4)));
typedef float f32x4 __attribute__((ext_vector_type(4)));
typedef unsigned short u16;
typedef unsigned int u32;

static __device__ __forceinline__ u16 f2bf(float f) {
  unsigned u = __float_as_uint(f);
  u += 0x7fffu + ((u >> 16) & 1u);  // round-to-nearest-even
  return (u16)(u >> 16);
}

#define GLDS(gp, lp) __builtin_amdgcn_global_load_lds( \
    (const __attribute__((address_space(1))) void*)(gp), \
    (__attribute__((address_space(3))) void*)(lp), 16, 0, 0)

// ---------------- fp32 -> bf16 elementwise convert ----------------
__global__ void cvt_k(const float* __restrict__ in, u16* __restrict__ out, int n) {
  int i = (blockIdx.x * 256 + threadIdx.x) * 8;
  if (i >= n) return;
  float4 a = *(const float4*)&in[i];
  float4 b = *(const float4*)&in[i + 4];
  bf16x8 u;
  u[0] = (short)f2bf(a.x); u[1] = (short)f2bf(a.y);
  u[2] = (short)f2bf(a.z); u[3] = (short)f2bf(a.w);
  u[4] = (short)f2bf(b.x); u[5] = (short)f2bf(b.y);
  u[6] = (short)f2bf(b.z); u[7] = (short)f2bf(b.w);
  *(bf16x8*)&out[i] = u;
}

// ---------------- fp32 [R][C] -> bf16 [C][R] transpose-convert ----------------
__global__ void trcvt_k(const float* __restrict__ in, u16* __restrict__ out, int R, int C) {
  __shared__ float t[32][33];
  int c0 = blockIdx.x * 32, r0 = blockIdx.y * 32;
  int tx = threadIdx.x & 7, ty = threadIdx.x >> 3;
  float4 v = *(const float4*)&in[(size_t)(r0 + ty) * C + c0 + tx * 4];
  t[ty][tx * 4 + 0] = v.x; t[ty][tx * 4 + 1] = v.y;
  t[ty][tx * 4 + 2] = v.z; t[ty][tx * 4 + 3] = v.w;
  __syncthreads();
  ushort4 o;
  o.x = f2bf(t[tx * 4 + 0][ty]); o.y = f2bf(t[tx * 4 + 1][ty]);
  o.z = f2bf(t[tx * 4 + 2][ty]); o.w = f2bf(t[tx * 4 + 3][ty]);
  *(ushort4*)&out[(size_t)(c0 + ty) * R + r0 + tx * 4] = o;
}

// ---------------- bf16 GEMM, BK=64, XOR-swizzled LDS, 2-barrier loop ----------------
// A [M][K] row-major, Bt [N][K] row-major. Tile = (WM*64) x 128; WM*2 waves,
// wave (wr,wc) owns a 64x64 sub-tile. BK=64: rows are 128B -> frag ds_read_b128
// would be a 16-way bank conflict, so LDS content is XOR-swizzled
// (byte ^= (row&7)<<4), staged via GLDS with pre-swizzled SOURCE (rule #21, same
// verified geometry as attn's K tile) and read back with the same XOR.
// MODE 0: scatter into Q (pre-scaled by 0.125*log2e) [bh][s][dh], K [bh][s][dh],
//         VT [bh][dh][s].  MODE 1: fp32 out [M][N] + bias.
template<int MODE, int WM>
__global__ __launch_bounds__(WM * 128)
void gemm_k(const u16* __restrict__ A, const u16* __restrict__ Bt,
            int M, int N, int K,
            u16* __restrict__ Qo, u16* __restrict__ Ko, u16* __restrict__ VTo,
            float* __restrict__ Co, const float* __restrict__ bias) {
  constexpr int T  = WM * 128;       // threads
  constexpr int BM = WM * 64;        // M-tile
  constexpr int RA = 4;              // A staging rounds (BM*128B / (T*16B)) == 4
  constexpr int RB = 1024 / T;       // B staging rounds
  __shared__ __align__(16) u16 As[BM * 64];
  __shared__ __align__(16) u16 Bs[128 * 64];
  const int tid = threadIdx.x;
  const int w = tid >> 6, l = tid & 63;
  const int lr = l & 15, lg = l >> 4;
  const int wr = w >> 1, wc = w & 1;
  const int m0 = blockIdx.y * BM, n0 = blockIdx.x * 128;
  const int swz = (lr & 7) << 4;

  f32x4 acc[4][4] = {};

  const int nk = K >> 6;
  for (int kt = 0; kt < nk; ++kt) {
    __syncthreads();                 // all waves done reading previous LDS tile
    const int k0 = kt * 64;
#pragma unroll
    for (int r2 = 0; r2 < RA; ++r2) {
      int c = r2 * T + tid;
      int row = c >> 3;
      int scolb = ((c & 7) * 16) ^ ((row & 7) << 4);   // inverse-swizzled source
      GLDS(A + (size_t)(m0 + row) * K + k0 + (scolb >> 1),
           (char*)As + (size_t)r2 * T * 16 + w * 1024);
    }
#pragma unroll
    for (int r2 = 0; r2 < RB; ++r2) {
      int c = r2 * T + tid;
      int row = c >> 3;
      int scolb = ((c & 7) * 16) ^ ((row & 7) << 4);
      GLDS(Bt + (size_t)(n0 + row) * K + k0 + (scolb >> 1),
           (char*)Bs + (size_t)r2 * T * 16 + w * 1024);
    }
    __syncthreads();                 // drains vmcnt(0): tile staged

#pragma unroll
    for (int kk = 0; kk < 2; ++kk) {
      bf16x8 af[4];
#pragma unroll
      for (int mi = 0; mi < 4; ++mi)
        af[mi] = *(const bf16x8*)((const char*)As +
                  ((wr * 64 + mi * 16 + lr) * 128 + ((kk * 64 + lg * 16) ^ swz)));
#pragma unroll
      for (int ni = 0; ni < 4; ++ni) {
        bf16x8 bfr = *(const bf16x8*)((const char*)Bs +
                  ((wc * 64 + ni * 16 + lr) * 128 + ((kk * 64 + lg * 16) ^ swz)));
#pragma unroll
        for (int mi = 0; mi < 4; ++mi)
          acc[mi][ni] = __builtin_amdgcn_mfma_f32_16x16x32_bf16(af[mi], bfr, acc[mi][ni], 0, 0, 0);
      }
    }
  }

#pragma unroll
  for (int mi = 0; mi < 4; ++mi) {
#pragma unroll
    for (int ni = 0; ni < 4; ++ni) {
#pragma unroll
      for (int r = 0; r < 4; ++r) {
        int gm = m0 + wr * 64 + mi * 16 + lg * 4 + r;
        int gn = n0 + wc * 64 + ni * 16 + lr;
        float v = acc[mi][ni][r];
        if (MODE == 0) {
          int which = gn >> 10, hd = gn & 1023;
          int b = gm >> 11, s = gm & 2047;
          int bh = b * NH + (hd >> 6), dh = hd & 63;
          if (which == 0)      Qo[((size_t)bh * NS + s) * NDH + dh] = f2bf(v * 0.1803368801111204f);
          else if (which == 1) Ko[((size_t)bh * NS + s) * NDH + dh] = f2bf(v);
          else                 VTo[((size_t)bh * NDH + dh) * NS + s] = f2bf(v);
        } else {
          Co[(size_t)gm * N + gn] = v + bias[gn];
        }
      }
    }
  }
}

// ---------------- causal flash attention, swapped-QK^T, in-register P ----------------
// Q (pre-scaled),K: [bh][S][DH] bf16; VT: [bh][DH][S] bf16. CTX: [B][S][H*DH] bf16.
// 8 WAVES (512 threads), wave w owns 16 q rows: qt*128 + w*16 + (0..15).
// TRIANGLE-PAIRED: block (bh, pr) runs q-tile `pr` then `15-pr` -> 36 K-tiles each.
// Grid (64,8): same-head blocks share an XCD L2. 2 blocks/CU = 16 waves/CU.
// KVBLK=64, double-buffered LDS (32KB); no online max (scores O(+-10) in log2
// domain); row-sum linear -> one cross-lane reduce per pass.
__global__ __launch_bounds__(512)
void attn_k(const u16* __restrict__ Q, const u16* __restrict__ Kg,
            const u16* __restrict__ VTg, u16* __restrict__ CTX) {
  const int bh = blockIdx.x;        // 0..63 (same-bh blocks -> same XCD)
  const int pr = blockIdx.y;        // 0..7
  const int tid = threadIdx.x, w = tid >> 6, l = tid & 63;
  const int lr = l & 15, lg = l >> 4;
  const u16* Qh  = Q   + (size_t)bh * NS * NDH;
  const u16* Kh  = Kg  + (size_t)bh * NS * NDH;
  const u16* Vth = VTg + (size_t)bh * NDH * NS;

  __shared__ __align__(16) u16 Ks[2][64 * 64];  // [key][dh], XOR-swizzled content
  __shared__ __align__(16) u16 Vs[2][64 * 64];  // [dh][key], XOR-swizzled content

  // staging: 512 threads x 16B x (K,V) = full 8KB K-tile + 8KB V-tile in one round.
  // LDS dest lane-linear (GLDS); source pre-applies the inverse swizzle (rule #21).
  const int srow_ = tid >> 3;              // 0..63
  const int colb  = (tid & 7) * 16;        // byte col within 128B row
  const int scolb = colb ^ ((srow_ & 7) << 4);
  const int kSrcOff = srow_ * NDH + (scolb >> 1);  // elems into K tile (stride 64)
  const int vSrcOff = srow_ * NS + (scolb >> 1);   // elems into VT (stride 2048)
  const int ldsOff  = w * 1024;            // wave-uniform byte base (64 lanes x 16B)

#define STAGE(t, buf) do {                                          \
    GLDS(Kh  + (size_t)(t) * 64 * NDH + kSrcOff, (char*)Ks[buf] + ldsOff); \
    GLDS(Vth + (size_t)(t) * 64       + vSrcOff, (char*)Vs[buf] + ldsOff); \
  } while (0)

  const int swz = (lr & 7) << 4;
  const int b = bh >> 4, h = bh & 15;

  for (int pass = 0; pass < 2; ++pass) {
    const int qt = pass == 0 ? pr : 15 - pr;

    // Q fragments (B operand): col = q = lr, k(dh) = kk*32 + lg*8 + j
    const int qrow = qt * 128 + w * 16 + lr;
    bf16x8 qf[2];
    qf[0] = *(const bf16x8*)&Qh[(size_t)qrow * NDH + 0 * 32 + lg * 8];
    qf[1] = *(const bf16x8*)&Qh[(size_t)qrow * NDH + 1 * 32 + lg * 8];

    f32x4 o[4] = {};
    float lrun = 0.f;                 // per-lane PARTIAL row-sum
    const int qmin = qt * 128 + w * 16;   // wave's lowest q row

    __syncthreads();   // all waves done reading previous pass's LDS
    STAGE(0, 0);
    __syncthreads();   // drains vmcnt(0): tile 0 staged

    const int NT = 2 * qt + 2;
    for (int kt = 0; kt < NT; ++kt) {
      const int cur = kt & 1;
      if (kt + 1 < NT) STAGE(kt + 1, cur ^ 1);   // prefetch; lands under compute

      // ---- S^T = K Q^T : sc[kg][r] = S_log2[key=kt*64+kg*16+lg*4+r][q=lr] ----
      f32x4 sc[4] = {};
#pragma unroll
      for (int kk = 0; kk < 2; ++kk) {
#pragma unroll
        for (int kg = 0; kg < 4; ++kg) {
          bf16x8 kf = *(const bf16x8*)((const char*)Ks[cur] +
                       ((kg * 16 + lr) * 128 + ((kk * 64 + lg * 16) ^ swz)));
          sc[kg] = __builtin_amdgcn_mfma_f32_16x16x32_bf16(kf, qf[kk], sc[kg], 0, 0, 0);
        }
      }

      // ---- P = exp2(S) directly; accumulate partial sum (in-place into sc) ----
      float sum = 0.f;
      if (kt * 64 + 63 > qmin) {   // tile may need causal masking (wave-uniform)
#pragma unroll
        for (int kg = 0; kg < 4; ++kg)
#pragma unroll
          for (int r = 0; r < 4; ++r) {
            int kglob = kt * 64 + kg * 16 + lg * 4 + r;
            float e = (kglob > qrow) ? 0.f : exp2f(sc[kg][r]);
            sc[kg][r] = e; sum += e;
          }
      } else {
#pragma unroll
        for (int kg = 0; kg < 4; ++kg)
#pragma unroll
          for (int r = 0; r < 4; ++r) {
            float e = exp2f(sc[kg][r]);
            sc[kg][r] = e; sum += e;
          }
      }
      lrun += sum;

      // ---- PV: A = P (packed via v_cvt_pk_bf16_f32), B = V from Vs;
      //      shared k-map: key = half*32 + (j>>2)*16 + lg*4 + (j&3) ----
#pragma unroll
      for (int half = 0; half < 2; ++half) {
        union { u32 wd[4]; bf16x8 v; } pk;
#pragma unroll
        for (int w2 = 0; w2 < 4; ++w2) {
          float lo = sc[half * 2 + (w2 >> 1)][2 * (w2 & 1)];
          float hi = sc[half * 2 + (w2 >> 1)][2 * (w2 & 1) + 1];
          asm("v_cvt_pk_bf16_f32 %0, %1, %2" : "=v"(pk.wd[w2]) : "v"(lo), "v"(hi));
        }
        bf16x8 pf = pk.v;
#pragma unroll
        for (int dhg = 0; dhg < 4; ++dhg) {
          const char* vrow = (const char*)Vs[cur] + (dhg * 16 + lr) * 128;
          bf16x4 va = *(const bf16x4*)(vrow + ((half * 64 + lg * 8) ^ swz));
          bf16x4 vb = *(const bf16x4*)(vrow + ((half * 64 + 32 + lg * 8) ^ swz));
          bf16x8 vf = __builtin_shufflevector(va, vb, 0, 1, 2, 3, 4, 5, 6, 7);
          o[dhg] = __builtin_amdgcn_mfma_f32_16x16x32_bf16(pf, vf, o[dhg], 0, 0, 0);
        }
      }

      __syncthreads();   // drains prefetch + protects buffer reuse
    }

    // ---- single deferred cross-lane reduce of the row-sum, write CTX ----
    lrun += __shfl_xor(lrun, 16);
    lrun += __shfl_xor(lrun, 32);
    float linv = 1.0f / lrun;
#pragma unroll
    for (int r = 0; r < 4; ++r) {
      float lq = __shfl(linv, (l & 48) | (lg * 4 + r));
      int srow = qt * 128 + w * 16 + lg * 4 + r;
      size_t base = ((size_t)(b * NS + srow)) * (NH * NDH) + h * NDH;
#pragma unroll
      for (int dhg = 0; dhg < 4; ++dhg)
        CTX[base + dhg * 16 + lr] = f2bf(o[dhg][r] * lq);
    }
  }
#undef STAGE
}

// ---------------- launch ----------------
extern "C" void kernel_launch(void* const* d_in, const int* in_sizes, int n_in,
                              void* d_out, int out_size, void* d_ws, size_t ws_size,
                              hipStream_t stream) {
  const float* payload = (const float*)d_in[0];
  const float* w_qkv   = (const float*)d_in[1];
  const float* w_out   = (const float*)d_in[2];
  const float* b_out   = (const float*)d_in[3];
  float* out = (float*)d_out;

  char* ws = (char*)d_ws;
  size_t o0 = 0;
  u16* Xb    = (u16*)(ws + o0); o0 += (size_t)8192 * 1024 * 2;
  u16* Wqkvt = (u16*)(ws + o0); o0 += (size_t)3072 * 1024 * 2;
  u16* Woutt = (u16*)(ws + o0); o0 += (size_t)1024 * 1024 * 2;
  u16* Qb    = (u16*)(ws + o0); o0 += (size_t)64 * 2048 * 64 * 2;
  u16* Kb    = (u16*)(ws + o0); o0 += (size_t)64 * 2048 * 64 * 2;
  u16* VTb   = (u16*)(ws + o0); o0 += (size_t)64 * 64 * 2048 * 2;  // [bh][dh][s]
  u16* CTX   = Xb;  // alias: GEMM0 finishes reading Xb before attn writes CTX

  cvt_k<<<dim3(4096), dim3(256), 0, stream>>>(payload, Xb, 8192 * 1024);
  trcvt_k<<<dim3(96, 32), dim3(256), 0, stream>>>(w_qkv, Wqkvt, 1024, 3072);
  trcvt_k<<<dim3(32, 32), dim3(256), 0, stream>>>(w_out, Woutt, 1024, 1024);
  gemm_k<0, 4><<<dim3(24, 32), dim3(512), 0, stream>>>(Xb, Wqkvt, 8192, 3072, 1024,
                                                       Qb, Kb, VTb, nullptr, nullptr);
  attn_k<<<dim3(64, 8), dim3(512), 0, stream>>>(Qb, Kb, VTb, CTX);
  gemm_k<1, 2><<<dim3(8, 64), dim3(256), 0, stream>>>(CTX, Woutt, 8192, 1024, 1024,
                                                      nullptr, nullptr, nullptr, out, b_out);
}